// Round 3
// baseline (857.702 us; speedup 1.0000x reference)
//
#include <hip/hip_runtime.h>

#define B 8
#define NF 4096
#define NT 4096
#define D_HID 128
#define D_OUT 32
#define D_V 16

__device__ inline float fast_exp2(float x) {
#if __has_builtin(__builtin_amdgcn_exp2f)
  return __builtin_amdgcn_exp2f(x);
#else
  return exp2f(x);
#endif
}

__device__ inline const float* uniform_ptr(const float* p) {
  uint64_t u = (uint64_t)p;
  uint32_t lo = __builtin_amdgcn_readfirstlane((uint32_t)u);
  uint32_t hi = __builtin_amdgcn_readfirstlane((uint32_t)(u >> 32));
  return (const float*)(((uint64_t)hi << 32) | lo);
}

// ---------------- MLP: [N,3] -> relu(x W1 + b1) W2 + b2 -> [N,32] ----------------
__global__ __launch_bounds__(256) void mlp_kernel(
    const float* __restrict__ x, const float* __restrict__ W1,
    const float* __restrict__ b1, const float* __restrict__ W2,
    const float* __restrict__ b2, float* __restrict__ out) {
  const int t = blockIdx.x * 256 + threadIdx.x;
  const float x0 = x[t * 3 + 0];
  const float x1 = x[t * 3 + 1];
  const float x2 = x[t * 3 + 2];
  float acc[D_OUT];
#pragma unroll
  for (int o = 0; o < D_OUT; ++o) acc[o] = b2[o];
#pragma unroll 4
  for (int h = 0; h < D_HID; ++h) {
    float hv = fmaf(x2, W1[2 * D_HID + h],
               fmaf(x1, W1[1 * D_HID + h],
               fmaf(x0, W1[0 * D_HID + h], b1[h])));
    hv = fmaxf(hv, 0.0f);
#pragma unroll
    for (int o = 0; o < D_OUT; ++o) acc[o] = fmaf(hv, W2[h * D_OUT + o], acc[o]);
  }
  float* op = out + (size_t)t * D_OUT;
#pragma unroll
  for (int o = 0; o < D_OUT; ++o) op[o] = acc[o];
}

// ------------- fused L1-dist + softmax(over i) + PV, flash style over NF -------------
// thread = one j column; wave-uniform Wk/values rows; SoA partials per NF-chunk.
__global__ __launch_bounds__(256, 4) void attn_kernel(
    const float* __restrict__ Wk, const float* __restrict__ Wq,
    const float* __restrict__ Vf, float* __restrict__ partial,
    int nchunks, int chlen) {
  const int j = blockIdx.x * 256 + threadIdx.x;
  const int b = blockIdx.y;
  const int c = blockIdx.z;
  const int i0 = c * chlen;

  // load q row (once), per-lane
  const float* qp = Wq + ((size_t)b * NT + j) * D_OUT;
  float q[D_OUT];
#pragma unroll
  for (int d = 0; d < D_OUT; d += 4) {
    float4 t4 = *reinterpret_cast<const float4*>(qp + d);
    q[d + 0] = t4.x; q[d + 1] = t4.y; q[d + 2] = t4.z; q[d + 3] = t4.w;
  }

  constexpr float C2 = -0.72134752044448170368f;  // -log2(e)/2

  float m = -1e30f;  // running max in log2 domain; first iter self-normalizes
  float l = 0.0f;
  float acc[D_V];
#pragma unroll
  for (int k = 0; k < D_V; ++k) acc[k] = 0.0f;

  // wave-uniform row pointers -> keep in SGPRs
  const float* kr = uniform_ptr(Wk + ((size_t)b * NF + i0) * D_OUT);
  const float* vr = uniform_ptr(Vf + ((size_t)b * NF + i0) * D_V);

  for (int i = 0; i < chlen; ++i) {
    const float4 k0 = *reinterpret_cast<const float4*>(kr + 0);
    const float4 k1 = *reinterpret_cast<const float4*>(kr + 4);
    const float4 k2 = *reinterpret_cast<const float4*>(kr + 8);
    const float4 k3 = *reinterpret_cast<const float4*>(kr + 12);
    const float4 k4 = *reinterpret_cast<const float4*>(kr + 16);
    const float4 k5 = *reinterpret_cast<const float4*>(kr + 20);
    const float4 k6 = *reinterpret_cast<const float4*>(kr + 24);
    const float4 k7 = *reinterpret_cast<const float4*>(kr + 28);
    const float4 v0 = *reinterpret_cast<const float4*>(vr + 0);
    const float4 v1 = *reinterpret_cast<const float4*>(vr + 4);
    const float4 v2 = *reinterpret_cast<const float4*>(vr + 8);
    const float4 v3 = *reinterpret_cast<const float4*>(vr + 12);

    // 4 independent chains, 2 VALU/dim (v_sub + v_add with |src| modifier)
    float a0 = fabsf(k0.x - q[0]);
    float a1 = fabsf(k0.y - q[1]);
    float a2 = fabsf(k0.z - q[2]);
    float a3 = fabsf(k0.w - q[3]);
    a0 += fabsf(k1.x - q[4]);
    a1 += fabsf(k1.y - q[5]);
    a2 += fabsf(k1.z - q[6]);
    a3 += fabsf(k1.w - q[7]);
    a0 += fabsf(k2.x - q[8]);
    a1 += fabsf(k2.y - q[9]);
    a2 += fabsf(k2.z - q[10]);
    a3 += fabsf(k2.w - q[11]);
    a0 += fabsf(k3.x - q[12]);
    a1 += fabsf(k3.y - q[13]);
    a2 += fabsf(k3.z - q[14]);
    a3 += fabsf(k3.w - q[15]);
    a0 += fabsf(k4.x - q[16]);
    a1 += fabsf(k4.y - q[17]);
    a2 += fabsf(k4.z - q[18]);
    a3 += fabsf(k4.w - q[19]);
    a0 += fabsf(k5.x - q[20]);
    a1 += fabsf(k5.y - q[21]);
    a2 += fabsf(k5.z - q[22]);
    a3 += fabsf(k5.w - q[23]);
    a0 += fabsf(k6.x - q[24]);
    a1 += fabsf(k6.y - q[25]);
    a2 += fabsf(k6.z - q[26]);
    a3 += fabsf(k6.w - q[27]);
    a0 += fabsf(k7.x - q[28]);
    a1 += fabsf(k7.y - q[29]);
    a2 += fabsf(k7.z - q[30]);
    a3 += fabsf(k7.w - q[31]);
    const float dist = (a0 + a1) + (a2 + a3);

    const float d2 = dist * dist;
    float parg = fmaf(C2, d2, -m);  // s2 - m
    if (__any(parg > 4.0f)) {       // rare, wave-uniform rescale
      const float s2 = C2 * d2;
      const float mn = fmaxf(m, s2);
      const float al = fast_exp2(m - mn);
      l *= al;
#pragma unroll
      for (int k = 0; k < D_V; ++k) acc[k] *= al;
      m = mn;
      parg = s2 - m;
    }
    const float p = fast_exp2(parg);

    l += p;
    acc[0]  = fmaf(p, v0.x, acc[0]);
    acc[1]  = fmaf(p, v0.y, acc[1]);
    acc[2]  = fmaf(p, v0.z, acc[2]);
    acc[3]  = fmaf(p, v0.w, acc[3]);
    acc[4]  = fmaf(p, v1.x, acc[4]);
    acc[5]  = fmaf(p, v1.y, acc[5]);
    acc[6]  = fmaf(p, v1.z, acc[6]);
    acc[7]  = fmaf(p, v1.w, acc[7]);
    acc[8]  = fmaf(p, v2.x, acc[8]);
    acc[9]  = fmaf(p, v2.y, acc[9]);
    acc[10] = fmaf(p, v2.z, acc[10]);
    acc[11] = fmaf(p, v2.w, acc[11]);
    acc[12] = fmaf(p, v3.x, acc[12]);
    acc[13] = fmaf(p, v3.y, acc[13]);
    acc[14] = fmaf(p, v3.z, acc[14]);
    acc[15] = fmaf(p, v3.w, acc[15]);

    kr += D_OUT;
    vr += D_V;
  }

  // SoA partials: partial[f * (nchunks*B*NT) + (c*B + b)*NT + j] -> coalesced
  const size_t fstride = (size_t)nchunks * B * NT;
  float* ps = partial + ((size_t)c * B + b) * NT + j;
  ps[0] = m;
  ps[fstride] = l;
#pragma unroll
  for (int k = 0; k < D_V; ++k) ps[(size_t)(2 + k) * fstride] = acc[k];
}

// ---------------- combine NF-chunk partials -> output ----------------
__global__ __launch_bounds__(256) void combine_kernel(
    const float* __restrict__ partial, float* __restrict__ out, int nchunks) {
  const int t = blockIdx.x * 256 + threadIdx.x;  // = b*NT + j
  const size_t fstride = (size_t)nchunks * B * NT;
  // element for chunk c, field f: partial[f*fstride + c*(B*NT) + t]
  float M = -1e30f;
  for (int c = 0; c < nchunks; ++c)
    M = fmaxf(M, partial[(size_t)c * (B * NT) + t]);
  float L = 0.0f;
  float acc[D_V];
#pragma unroll
  for (int k = 0; k < D_V; ++k) acc[k] = 0.0f;
  for (int c = 0; c < nchunks; ++c) {
    const size_t base = (size_t)c * (B * NT) + t;
    const float w = fast_exp2(partial[base] - M);
    L = fmaf(w, partial[fstride + base], L);
#pragma unroll
    for (int k = 0; k < D_V; ++k)
      acc[k] = fmaf(w, partial[(size_t)(2 + k) * fstride + base], acc[k]);
  }
  const float inv = 1.0f / L;
  float* op = out + (size_t)t * D_V;
#pragma unroll
  for (int k = 0; k < D_V; ++k) op[k] = acc[k] * inv;
}

extern "C" void kernel_launch(void* const* d_in, const int* in_sizes, int n_in,
                              void* d_out, int out_size, void* d_ws, size_t ws_size,
                              hipStream_t stream) {
  const float* coords_f = (const float*)d_in[0];
  const float* values_f = (const float*)d_in[1];
  const float* coords_t = (const float*)d_in[2];
  const float* Wk1 = (const float*)d_in[3];
  const float* bk1 = (const float*)d_in[4];
  const float* Wk2 = (const float*)d_in[5];
  const float* bk2 = (const float*)d_in[6];
  const float* Wq1 = (const float*)d_in[7];
  const float* bq1 = (const float*)d_in[8];
  const float* Wq2 = (const float*)d_in[9];
  const float* bq2 = (const float*)d_in[10];
  float* out = (float*)d_out;

  float* Wk = (float*)d_ws;                        // 4 MB
  float* Wq = Wk + (size_t)B * NF * D_OUT;         // 4 MB
  float* partial = Wq + (size_t)B * NT * D_OUT;

  const size_t fixed = (size_t)(B * NF * D_OUT + B * NT * D_OUT) * sizeof(float);
  int nchunks = 16;
  while (nchunks > 1 &&
         fixed + (size_t)B * NT * nchunks * 18 * sizeof(float) > ws_size)
    nchunks >>= 1;
  const int chlen = NF / nchunks;

  hipLaunchKernelGGL(mlp_kernel, dim3(B * NF / 256), dim3(256), 0, stream,
                     coords_f, Wk1, bk1, Wk2, bk2, Wk);
  hipLaunchKernelGGL(mlp_kernel, dim3(B * NT / 256), dim3(256), 0, stream,
                     coords_t, Wq1, bq1, Wq2, bq2, Wq);
  hipLaunchKernelGGL(attn_kernel, dim3(NT / 256, B, nchunks), dim3(256), 0, stream,
                     Wk, Wq, values_f, partial, nchunks, chlen);
  hipLaunchKernelGGL(combine_kernel, dim3(B * NT / 256), dim3(256), 0, stream,
                     partial, out, nchunks);
}

// Round 5
// 523.890 us; speedup vs baseline: 1.6372x; 1.6372x over previous
//
#include <hip/hip_runtime.h>

#define B 8
#define NF 4096
#define NT 4096
#define D_HID 128
#define D_OUT 32
#define D_V 16

__device__ inline float fast_exp2(float x) {
#if __has_builtin(__builtin_amdgcn_exp2f)
  return __builtin_amdgcn_exp2f(x);
#else
  return exp2f(x);
#endif
}

// ---------------- MLP: [N,3] -> relu(x W1 + b1) W2 + b2 -> [N,32] ----------------
// Weights staged in LDS (ds_read broadcast pipelines; scalar s_load serializes).
__global__ __launch_bounds__(256) void mlp_kernel(
    const float* __restrict__ x, const float* __restrict__ W1,
    const float* __restrict__ b1, const float* __restrict__ W2,
    const float* __restrict__ b2, float* __restrict__ out) {
  __shared__ float sW1[3 * D_HID];
  __shared__ float sb1[D_HID];
  __shared__ float sW2[D_HID * D_OUT];
  __shared__ float sb2[D_OUT];
  const int tid = threadIdx.x;
  for (int idx = tid; idx < D_HID * D_OUT; idx += 256) sW2[idx] = W2[idx];
  for (int idx = tid; idx < 3 * D_HID; idx += 256) sW1[idx] = W1[idx];
  if (tid < D_HID) sb1[tid] = b1[tid];
  if (tid < D_OUT) sb2[tid] = b2[tid];
  __syncthreads();

  const int t = blockIdx.x * 256 + tid;
  const float x0 = x[t * 3 + 0];
  const float x1 = x[t * 3 + 1];
  const float x2 = x[t * 3 + 2];
  float acc[D_OUT];
#pragma unroll
  for (int o = 0; o < D_OUT; ++o) acc[o] = sb2[o];
#pragma unroll 4
  for (int h = 0; h < D_HID; ++h) {
    float hv = fmaf(x2, sW1[2 * D_HID + h],
               fmaf(x1, sW1[1 * D_HID + h],
               fmaf(x0, sW1[0 * D_HID + h], sb1[h])));
    hv = fmaxf(hv, 0.0f);
    const float4* w2r = reinterpret_cast<const float4*>(&sW2[h * D_OUT]);
#pragma unroll
    for (int o4 = 0; o4 < D_OUT / 4; ++o4) {
      const float4 w = w2r[o4];
      acc[o4 * 4 + 0] = fmaf(hv, w.x, acc[o4 * 4 + 0]);
      acc[o4 * 4 + 1] = fmaf(hv, w.y, acc[o4 * 4 + 1]);
      acc[o4 * 4 + 2] = fmaf(hv, w.z, acc[o4 * 4 + 2]);
      acc[o4 * 4 + 3] = fmaf(hv, w.w, acc[o4 * 4 + 3]);
    }
  }
  float* op = out + (size_t)t * D_OUT;
#pragma unroll
  for (int o = 0; o < D_OUT; o += 4) {
    float4 w = make_float4(acc[o], acc[o + 1], acc[o + 2], acc[o + 3]);
    *reinterpret_cast<float4*>(op + o) = w;
  }
}

// ------------- fused L1-dist + softmax(over i) + PV, flash style over NF -------------
// thread = one j column; per-lane vector loads (broadcast via L1);
// explicit ping-pong register double-buffer: prefetch row i+2 while computing row i.
__global__ __launch_bounds__(256, 3) void attn_kernel(
    const float* __restrict__ Wk, const float* __restrict__ Wq,
    const float* __restrict__ Vf, float* __restrict__ partial,
    int nchunks, int chlen) {
  const int j = blockIdx.x * 256 + threadIdx.x;
  const int b = blockIdx.y;
  const int c = blockIdx.z;
  const int i0 = c * chlen;

  // load q row (once), per-lane
  const float* qp = Wq + ((size_t)b * NT + j) * D_OUT;
  float q[D_OUT];
#pragma unroll
  for (int d = 0; d < D_OUT; d += 4) {
    float4 t4 = *reinterpret_cast<const float4*>(qp + d);
    q[d + 0] = t4.x; q[d + 1] = t4.y; q[d + 2] = t4.z; q[d + 3] = t4.w;
  }

  constexpr float C2 = -0.72134752044448170368f;  // -log2(e)/2

  float m = -1e30f;  // running max in log2 domain; first iter self-normalizes
  float l = 0.0f;
  float acc[D_V];
#pragma unroll
  for (int k = 0; k < D_V; ++k) acc[k] = 0.0f;

  const float* kr = Wk + ((size_t)b * NF + i0) * D_OUT;
  const float* vr = Vf + ((size_t)b * NF + i0) * D_V;

  float4 ka[8], va[4], kb[8], vb[4];

#define LOADK(dst, base, ROW)                                                  \
  {                                                                            \
    dst[0] = *reinterpret_cast<const float4*>(base + (ROW)*D_OUT + 0);         \
    dst[1] = *reinterpret_cast<const float4*>(base + (ROW)*D_OUT + 4);         \
    dst[2] = *reinterpret_cast<const float4*>(base + (ROW)*D_OUT + 8);         \
    dst[3] = *reinterpret_cast<const float4*>(base + (ROW)*D_OUT + 12);        \
    dst[4] = *reinterpret_cast<const float4*>(base + (ROW)*D_OUT + 16);        \
    dst[5] = *reinterpret_cast<const float4*>(base + (ROW)*D_OUT + 20);        \
    dst[6] = *reinterpret_cast<const float4*>(base + (ROW)*D_OUT + 24);        \
    dst[7] = *reinterpret_cast<const float4*>(base + (ROW)*D_OUT + 28);        \
  }
#define LOADV(dst, base, ROW)                                                  \
  {                                                                            \
    dst[0] = *reinterpret_cast<const float4*>(base + (ROW)*D_V + 0);           \
    dst[1] = *reinterpret_cast<const float4*>(base + (ROW)*D_V + 4);           \
    dst[2] = *reinterpret_cast<const float4*>(base + (ROW)*D_V + 8);           \
    dst[3] = *reinterpret_cast<const float4*>(base + (ROW)*D_V + 12);          \
  }

  auto compute = [&](const float4* kk, const float4* vv) {
    float a0 = fabsf(kk[0].x - q[0]);
    float a1 = fabsf(kk[0].y - q[1]);
    float a2 = fabsf(kk[0].z - q[2]);
    float a3 = fabsf(kk[0].w - q[3]);
    a0 += fabsf(kk[1].x - q[4]);
    a1 += fabsf(kk[1].y - q[5]);
    a2 += fabsf(kk[1].z - q[6]);
    a3 += fabsf(kk[1].w - q[7]);
    a0 += fabsf(kk[2].x - q[8]);
    a1 += fabsf(kk[2].y - q[9]);
    a2 += fabsf(kk[2].z - q[10]);
    a3 += fabsf(kk[2].w - q[11]);
    a0 += fabsf(kk[3].x - q[12]);
    a1 += fabsf(kk[3].y - q[13]);
    a2 += fabsf(kk[3].z - q[14]);
    a3 += fabsf(kk[3].w - q[15]);
    a0 += fabsf(kk[4].x - q[16]);
    a1 += fabsf(kk[4].y - q[17]);
    a2 += fabsf(kk[4].z - q[18]);
    a3 += fabsf(kk[4].w - q[19]);
    a0 += fabsf(kk[5].x - q[20]);
    a1 += fabsf(kk[5].y - q[21]);
    a2 += fabsf(kk[5].z - q[22]);
    a3 += fabsf(kk[5].w - q[23]);
    a0 += fabsf(kk[6].x - q[24]);
    a1 += fabsf(kk[6].y - q[25]);
    a2 += fabsf(kk[6].z - q[26]);
    a3 += fabsf(kk[6].w - q[27]);
    a0 += fabsf(kk[7].x - q[28]);
    a1 += fabsf(kk[7].y - q[29]);
    a2 += fabsf(kk[7].z - q[30]);
    a3 += fabsf(kk[7].w - q[31]);
    const float dist = (a0 + a1) + (a2 + a3);

    const float d2 = dist * dist;
    float parg = fmaf(C2, d2, -m);  // s2 - m
    if (__any(parg > 4.0f)) {       // rare, wave-uniform rescale
      const float s2 = C2 * d2;
      const float mn = fmaxf(m, s2);
      const float al = fast_exp2(m - mn);
      l *= al;
#pragma unroll
      for (int k = 0; k < D_V; ++k) acc[k] *= al;
      m = mn;
      parg = s2 - m;
    }
    const float p = fast_exp2(parg);

    l += p;
    acc[0]  = fmaf(p, vv[0].x, acc[0]);
    acc[1]  = fmaf(p, vv[0].y, acc[1]);
    acc[2]  = fmaf(p, vv[0].z, acc[2]);
    acc[3]  = fmaf(p, vv[0].w, acc[3]);
    acc[4]  = fmaf(p, vv[1].x, acc[4]);
    acc[5]  = fmaf(p, vv[1].y, acc[5]);
    acc[6]  = fmaf(p, vv[1].z, acc[6]);
    acc[7]  = fmaf(p, vv[1].w, acc[7]);
    acc[8]  = fmaf(p, vv[2].x, acc[8]);
    acc[9]  = fmaf(p, vv[2].y, acc[9]);
    acc[10] = fmaf(p, vv[2].z, acc[10]);
    acc[11] = fmaf(p, vv[2].w, acc[11]);
    acc[12] = fmaf(p, vv[3].x, acc[12]);
    acc[13] = fmaf(p, vv[3].y, acc[13]);
    acc[14] = fmaf(p, vv[3].z, acc[14]);
    acc[15] = fmaf(p, vv[3].w, acc[15]);
  };

  // software pipeline: A holds row i, B holds row i+1; prefetch i+1, i+2.
  LOADK(ka, kr, 0)
  LOADV(va, vr, 0)
  int i = 0;
  for (; i < chlen - 2; i += 2) {
    LOADK(kb, kr, 1)
    LOADV(vb, vr, 1)
    compute(ka, va);
    LOADK(ka, kr, 2)
    LOADV(va, vr, 2)
    compute(kb, vb);
    kr += 2 * D_OUT;
    vr += 2 * D_V;
  }
  // tail: i == chlen-2; A = row chlen-2 already loaded
  LOADK(kb, kr, 1)
  LOADV(vb, vr, 1)
  compute(ka, va);
  compute(kb, vb);

#undef LOADK
#undef LOADV

  // SoA partials: partial[f * (nchunks*B*NT) + (c*B + b)*NT + j] -> coalesced
  const size_t fstride = (size_t)nchunks * B * NT;
  float* ps = partial + ((size_t)c * B + b) * NT + j;
  ps[0] = m;
  ps[fstride] = l;
#pragma unroll
  for (int k = 0; k < D_V; ++k) ps[(size_t)(2 + k) * fstride] = acc[k];
}

// ---------------- combine NF-chunk partials -> output ----------------
__global__ __launch_bounds__(256) void combine_kernel(
    const float* __restrict__ partial, float* __restrict__ out, int nchunks) {
  const int t = blockIdx.x * 256 + threadIdx.x;  // = b*NT + j
  const size_t fstride = (size_t)nchunks * B * NT;
  float M = -1e30f;
  for (int c = 0; c < nchunks; ++c)
    M = fmaxf(M, partial[(size_t)c * (B * NT) + t]);
  float L = 0.0f;
  float acc[D_V];
#pragma unroll
  for (int k = 0; k < D_V; ++k) acc[k] = 0.0f;
  for (int c = 0; c < nchunks; ++c) {
    const size_t base = (size_t)c * (B * NT) + t;
    const float w = fast_exp2(partial[base] - M);
    L = fmaf(w, partial[fstride + base], L);
#pragma unroll
    for (int k = 0; k < D_V; ++k)
      acc[k] = fmaf(w, partial[(size_t)(2 + k) * fstride + base], acc[k]);
  }
  const float inv = 1.0f / L;
  float* op = out + (size_t)t * D_V;
#pragma unroll
  for (int k = 0; k < D_V; ++k) op[k] = acc[k] * inv;
}

extern "C" void kernel_launch(void* const* d_in, const int* in_sizes, int n_in,
                              void* d_out, int out_size, void* d_ws, size_t ws_size,
                              hipStream_t stream) {
  const float* coords_f = (const float*)d_in[0];
  const float* values_f = (const float*)d_in[1];
  const float* coords_t = (const float*)d_in[2];
  const float* Wk1 = (const float*)d_in[3];
  const float* bk1 = (const float*)d_in[4];
  const float* Wk2 = (const float*)d_in[5];
  const float* bk2 = (const float*)d_in[6];
  const float* Wq1 = (const float*)d_in[7];
  const float* bq1 = (const float*)d_in[8];
  const float* Wq2 = (const float*)d_in[9];
  const float* bq2 = (const float*)d_in[10];
  float* out = (float*)d_out;

  float* Wk = (float*)d_ws;                        // 4 MB
  float* Wq = Wk + (size_t)B * NF * D_OUT;         // 4 MB
  float* partial = Wq + (size_t)B * NT * D_OUT;

  const size_t fixed = (size_t)(B * NF * D_OUT + B * NT * D_OUT) * sizeof(float);
  int nchunks = 16;
  while (nchunks > 1 &&
         fixed + (size_t)B * NT * nchunks * 18 * sizeof(float) > ws_size)
    nchunks >>= 1;
  const int chlen = NF / nchunks;

  hipLaunchKernelGGL(mlp_kernel, dim3(B * NF / 256), dim3(256), 0, stream,
                     coords_f, Wk1, bk1, Wk2, bk2, Wk);
  hipLaunchKernelGGL(mlp_kernel, dim3(B * NT / 256), dim3(256), 0, stream,
                     coords_t, Wq1, bq1, Wq2, bq2, Wq);
  hipLaunchKernelGGL(attn_kernel, dim3(NT / 256, B, nchunks), dim3(256), 0, stream,
                     Wk, Wq, values_f, partial, nchunks, chlen);
  hipLaunchKernelGGL(combine_kernel, dim3(B * NT / 256), dim3(256), 0, stream,
                     partial, out, nchunks);
}

// Round 6
// 460.861 us; speedup vs baseline: 1.8611x; 1.1368x over previous
//
#include <hip/hip_runtime.h>

#define B 8
#define NF 4096
#define NT 4096
#define D_HID 128
#define D_OUT 32
#define D_V 16
#define TILE_I 64

__device__ inline float fast_exp2(float x) {
#if __has_builtin(__builtin_amdgcn_exp2f)
  return __builtin_amdgcn_exp2f(x);
#else
  return exp2f(x);
#endif
}

// ---------------- MLP: [N,3] -> relu(x W1 + b1) W2 + b2 -> [N,32] ----------------
__global__ __launch_bounds__(256) void mlp_kernel(
    const float* __restrict__ x, const float* __restrict__ W1,
    const float* __restrict__ b1, const float* __restrict__ W2,
    const float* __restrict__ b2, float* __restrict__ out) {
  __shared__ float sW1[3 * D_HID];
  __shared__ float sb1[D_HID];
  __shared__ float sW2[D_HID * D_OUT];
  __shared__ float sb2[D_OUT];
  const int tid = threadIdx.x;
  for (int idx = tid; idx < D_HID * D_OUT; idx += 256) sW2[idx] = W2[idx];
  for (int idx = tid; idx < 3 * D_HID; idx += 256) sW1[idx] = W1[idx];
  if (tid < D_HID) sb1[tid] = b1[tid];
  if (tid < D_OUT) sb2[tid] = b2[tid];
  __syncthreads();

  const int t = blockIdx.x * 256 + tid;
  const float x0 = x[t * 3 + 0];
  const float x1 = x[t * 3 + 1];
  const float x2 = x[t * 3 + 2];
  float acc[D_OUT];
#pragma unroll
  for (int o = 0; o < D_OUT; ++o) acc[o] = sb2[o];
#pragma unroll 4
  for (int h = 0; h < D_HID; ++h) {
    float hv = fmaf(x2, sW1[2 * D_HID + h],
               fmaf(x1, sW1[1 * D_HID + h],
               fmaf(x0, sW1[0 * D_HID + h], sb1[h])));
    hv = fmaxf(hv, 0.0f);
    const float4* w2r = reinterpret_cast<const float4*>(&sW2[h * D_OUT]);
#pragma unroll
    for (int o4 = 0; o4 < D_OUT / 4; ++o4) {
      const float4 w = w2r[o4];
      acc[o4 * 4 + 0] = fmaf(hv, w.x, acc[o4 * 4 + 0]);
      acc[o4 * 4 + 1] = fmaf(hv, w.y, acc[o4 * 4 + 1]);
      acc[o4 * 4 + 2] = fmaf(hv, w.z, acc[o4 * 4 + 2]);
      acc[o4 * 4 + 3] = fmaf(hv, w.w, acc[o4 * 4 + 3]);
    }
  }
  float* op = out + (size_t)t * D_OUT;
#pragma unroll
  for (int o = 0; o < D_OUT; o += 4) {
    float4 w = make_float4(acc[o], acc[o + 1], acc[o + 2], acc[o + 3]);
    *reinterpret_cast<float4*>(op + o) = w;
  }
}

// ------------- fused L1-dist + softmax(over i) + PV, flash style over NF -------------
// Block-shared double-buffered LDS tiles of K/V (all lanes read the same rows).
// T14 async-split staging: issue next tile's 3 coalesced float4 loads at tile start,
// ds_write them after this tile's compute, one barrier per tile.
__global__ __launch_bounds__(256, 4) void attn_kernel(
    const float* __restrict__ Wk, const float* __restrict__ Wq,
    const float* __restrict__ Vf, float* __restrict__ partial,
    int nchunks, int chlen) {
  // per buffer: K tile 64x32 floats = 512 float4, V tile 64x16 = 256 float4 -> 12 KB
  __shared__ float4 sTile[2][768];
  const int tid = threadIdx.x;
  const int j = blockIdx.x * 256 + tid;
  const int b = blockIdx.y;
  const int c = blockIdx.z;
  const int i0 = c * chlen;
  const int ntiles = chlen / TILE_I;

  // load q row (once), per-lane
  const float* qp = Wq + ((size_t)b * NT + j) * D_OUT;
  float q[D_OUT];
#pragma unroll
  for (int d = 0; d < D_OUT; d += 4) {
    float4 t4 = *reinterpret_cast<const float4*>(qp + d);
    q[d + 0] = t4.x; q[d + 1] = t4.y; q[d + 2] = t4.z; q[d + 3] = t4.w;
  }

  constexpr float C2 = -0.72134752044448170368f;  // -log2(e)/2

  float m = -1e30f;  // running max in log2 domain; first iter self-normalizes
  float l = 0.0f;
  float acc[D_V];
#pragma unroll
  for (int k = 0; k < D_V; ++k) acc[k] = 0.0f;

  const float4* gK4 = reinterpret_cast<const float4*>(Wk + ((size_t)b * NF + i0) * D_OUT);
  const float4* gV4 = reinterpret_cast<const float4*>(Vf + ((size_t)b * NF + i0) * D_V);

  // prologue: stage tile 0 into buf 0
  {
    float4 f0 = gK4[tid];
    float4 f1 = gK4[256 + tid];
    float4 f2 = gV4[tid];
    sTile[0][tid] = f0;
    sTile[0][256 + tid] = f1;
    sTile[0][512 + tid] = f2;
  }
  __syncthreads();

  for (int t = 0; t < ntiles; ++t) {
    const int cur = t & 1;
    float4 f0, f1, f2;
    const bool more = (t + 1 < ntiles);
    if (more) {  // issue next tile's loads now; they fly during the 64-row compute
      f0 = gK4[(size_t)(t + 1) * 512 + tid];
      f1 = gK4[(size_t)(t + 1) * 512 + 256 + tid];
      f2 = gV4[(size_t)(t + 1) * 256 + tid];
    }
    const float4* kb4 = &sTile[cur][0];
    const float4* vb4 = &sTile[cur][512];
    for (int r = 0; r < TILE_I; ++r) {
      const float4 k0 = kb4[0];
      const float4 k1 = kb4[1];
      const float4 k2 = kb4[2];
      const float4 k3 = kb4[3];
      const float4 k4 = kb4[4];
      const float4 k5 = kb4[5];
      const float4 k6 = kb4[6];
      const float4 k7 = kb4[7];
      kb4 += 8;

      float a0 = fabsf(k0.x - q[0]);
      float a1 = fabsf(k0.y - q[1]);
      float a2 = fabsf(k0.z - q[2]);
      float a3 = fabsf(k0.w - q[3]);
      a0 += fabsf(k1.x - q[4]);
      a1 += fabsf(k1.y - q[5]);
      a2 += fabsf(k1.z - q[6]);
      a3 += fabsf(k1.w - q[7]);
      a0 += fabsf(k2.x - q[8]);
      a1 += fabsf(k2.y - q[9]);
      a2 += fabsf(k2.z - q[10]);
      a3 += fabsf(k2.w - q[11]);
      a0 += fabsf(k3.x - q[12]);
      a1 += fabsf(k3.y - q[13]);
      a2 += fabsf(k3.z - q[14]);
      a3 += fabsf(k3.w - q[15]);
      a0 += fabsf(k4.x - q[16]);
      a1 += fabsf(k4.y - q[17]);
      a2 += fabsf(k4.z - q[18]);
      a3 += fabsf(k4.w - q[19]);
      a0 += fabsf(k5.x - q[20]);
      a1 += fabsf(k5.y - q[21]);
      a2 += fabsf(k5.z - q[22]);
      a3 += fabsf(k5.w - q[23]);
      a0 += fabsf(k6.x - q[24]);
      a1 += fabsf(k6.y - q[25]);
      a2 += fabsf(k6.z - q[26]);
      a3 += fabsf(k6.w - q[27]);
      a0 += fabsf(k7.x - q[28]);
      a1 += fabsf(k7.y - q[29]);
      a2 += fabsf(k7.z - q[30]);
      a3 += fabsf(k7.w - q[31]);
      const float dist = (a0 + a1) + (a2 + a3);

      const float d2 = dist * dist;
      float parg = fmaf(C2, d2, -m);  // s2 - m
      if (__any(parg > 4.0f)) {       // rare, wave-uniform rescale
        const float s2 = C2 * d2;
        const float mn = fmaxf(m, s2);
        const float al = fast_exp2(m - mn);
        l *= al;
#pragma unroll
        for (int k = 0; k < D_V; ++k) acc[k] *= al;
        m = mn;
        parg = s2 - m;
      }
      const float p = fast_exp2(parg);

      const float4 v0 = vb4[0];
      const float4 v1 = vb4[1];
      const float4 v2 = vb4[2];
      const float4 v3 = vb4[3];
      vb4 += 4;

      l += p;
      acc[0]  = fmaf(p, v0.x, acc[0]);
      acc[1]  = fmaf(p, v0.y, acc[1]);
      acc[2]  = fmaf(p, v0.z, acc[2]);
      acc[3]  = fmaf(p, v0.w, acc[3]);
      acc[4]  = fmaf(p, v1.x, acc[4]);
      acc[5]  = fmaf(p, v1.y, acc[5]);
      acc[6]  = fmaf(p, v1.z, acc[6]);
      acc[7]  = fmaf(p, v1.w, acc[7]);
      acc[8]  = fmaf(p, v2.x, acc[8]);
      acc[9]  = fmaf(p, v2.y, acc[9]);
      acc[10] = fmaf(p, v2.z, acc[10]);
      acc[11] = fmaf(p, v2.w, acc[11]);
      acc[12] = fmaf(p, v3.x, acc[12]);
      acc[13] = fmaf(p, v3.y, acc[13]);
      acc[14] = fmaf(p, v3.z, acc[14]);
      acc[15] = fmaf(p, v3.w, acc[15]);
    }
    if (more) {  // write-late: implicit vmcnt wait is free (loads long since landed)
      const int nxt = cur ^ 1;
      sTile[nxt][tid] = f0;
      sTile[nxt][256 + tid] = f1;
      sTile[nxt][512 + tid] = f2;
    }
    __syncthreads();
  }

  // SoA partials: partial[f * (nchunks*B*NT) + (c*B + b)*NT + j] -> coalesced
  const size_t fstride = (size_t)nchunks * B * NT;
  float* ps = partial + ((size_t)c * B + b) * NT + j;
  ps[0] = m;
  ps[fstride] = l;
#pragma unroll
  for (int k = 0; k < D_V; ++k) ps[(size_t)(2 + k) * fstride] = acc[k];
}

// ---------------- combine NF-chunk partials -> output ----------------
__global__ __launch_bounds__(256) void combine_kernel(
    const float* __restrict__ partial, float* __restrict__ out, int nchunks) {
  const int t = blockIdx.x * 256 + threadIdx.x;  // = b*NT + j
  const size_t fstride = (size_t)nchunks * B * NT;
  float M = -1e30f;
  for (int c = 0; c < nchunks; ++c)
    M = fmaxf(M, partial[(size_t)c * (B * NT) + t]);
  float L = 0.0f;
  float acc[D_V];
#pragma unroll
  for (int k = 0; k < D_V; ++k) acc[k] = 0.0f;
  for (int c = 0; c < nchunks; ++c) {
    const size_t base = (size_t)c * (B * NT) + t;
    const float w = fast_exp2(partial[base] - M);
    L = fmaf(w, partial[fstride + base], L);
#pragma unroll
    for (int k = 0; k < D_V; ++k)
      acc[k] = fmaf(w, partial[(size_t)(2 + k) * fstride + base], acc[k]);
  }
  const float inv = 1.0f / L;
  float* op = out + (size_t)t * D_V;
#pragma unroll
  for (int k = 0; k < D_V; ++k) op[k] = acc[k] * inv;
}

extern "C" void kernel_launch(void* const* d_in, const int* in_sizes, int n_in,
                              void* d_out, int out_size, void* d_ws, size_t ws_size,
                              hipStream_t stream) {
  const float* coords_f = (const float*)d_in[0];
  const float* values_f = (const float*)d_in[1];
  const float* coords_t = (const float*)d_in[2];
  const float* Wk1 = (const float*)d_in[3];
  const float* bk1 = (const float*)d_in[4];
  const float* Wk2 = (const float*)d_in[5];
  const float* bk2 = (const float*)d_in[6];
  const float* Wq1 = (const float*)d_in[7];
  const float* bq1 = (const float*)d_in[8];
  const float* Wq2 = (const float*)d_in[9];
  const float* bq2 = (const float*)d_in[10];
  float* out = (float*)d_out;

  float* Wk = (float*)d_ws;                        // 4 MB
  float* Wq = Wk + (size_t)B * NF * D_OUT;         // 4 MB
  float* partial = Wq + (size_t)B * NT * D_OUT;

  const size_t fixed = (size_t)(B * NF * D_OUT + B * NT * D_OUT) * sizeof(float);
  int nchunks = 32;  // chlen = 128 = 2 tiles of 64
  while (nchunks > 1 &&
         fixed + (size_t)B * NT * nchunks * 18 * sizeof(float) > ws_size)
    nchunks >>= 1;
  const int chlen = NF / nchunks;

  hipLaunchKernelGGL(mlp_kernel, dim3(B * NF / 256), dim3(256), 0, stream,
                     coords_f, Wk1, bk1, Wk2, bk2, Wk);
  hipLaunchKernelGGL(mlp_kernel, dim3(B * NT / 256), dim3(256), 0, stream,
                     coords_t, Wq1, bq1, Wq2, bq2, Wq);
  hipLaunchKernelGGL(attn_kernel, dim3(NT / 256, B, nchunks), dim3(256), 0, stream,
                     Wk, Wq, values_f, partial, nchunks, chlen);
  hipLaunchKernelGGL(combine_kernel, dim3(B * NT / 256), dim3(256), 0, stream,
                     partial, out, nchunks);
}

// Round 7
// 428.397 us; speedup vs baseline: 2.0021x; 1.0758x over previous
//
#include <hip/hip_runtime.h>

#define B 8
#define NF 4096
#define NT 4096
#define D_HID 128
#define D_OUT 32
#define D_V 16
#define TILE_I 64

__device__ inline float fast_exp2(float x) {
#if __has_builtin(__builtin_amdgcn_exp2f)
  return __builtin_amdgcn_exp2f(x);
#else
  return exp2f(x);
#endif
}

// ---------------- MLP: [N,3] -> relu(x W1 + b1) W2 + b2 -> [N,32] ----------------
// 64-thread blocks: 512 blocks spread across 256 CUs (was 128 blocks = half idle).
__global__ __launch_bounds__(64) void mlp_kernel(
    const float* __restrict__ x, const float* __restrict__ W1,
    const float* __restrict__ b1, const float* __restrict__ W2,
    const float* __restrict__ b2, float* __restrict__ out) {
  __shared__ float sW1[3 * D_HID];
  __shared__ float sb1[D_HID];
  __shared__ float sW2[D_HID * D_OUT];
  __shared__ float sb2[D_OUT];
  const int tid = threadIdx.x;
  for (int idx = tid; idx < D_HID * D_OUT; idx += 64) sW2[idx] = W2[idx];
  for (int idx = tid; idx < 3 * D_HID; idx += 64) sW1[idx] = W1[idx];
  for (int idx = tid; idx < D_HID; idx += 64) sb1[idx] = b1[idx];
  if (tid < D_OUT) sb2[tid] = b2[tid];
  __syncthreads();

  const int t = blockIdx.x * 64 + tid;
  const float x0 = x[t * 3 + 0];
  const float x1 = x[t * 3 + 1];
  const float x2 = x[t * 3 + 2];
  float acc[D_OUT];
#pragma unroll
  for (int o = 0; o < D_OUT; ++o) acc[o] = sb2[o];
#pragma unroll 4
  for (int h = 0; h < D_HID; ++h) {
    float hv = fmaf(x2, sW1[2 * D_HID + h],
               fmaf(x1, sW1[1 * D_HID + h],
               fmaf(x0, sW1[0 * D_HID + h], sb1[h])));
    hv = fmaxf(hv, 0.0f);
    const float4* w2r = reinterpret_cast<const float4*>(&sW2[h * D_OUT]);
#pragma unroll
    for (int o4 = 0; o4 < D_OUT / 4; ++o4) {
      const float4 w = w2r[o4];
      acc[o4 * 4 + 0] = fmaf(hv, w.x, acc[o4 * 4 + 0]);
      acc[o4 * 4 + 1] = fmaf(hv, w.y, acc[o4 * 4 + 1]);
      acc[o4 * 4 + 2] = fmaf(hv, w.z, acc[o4 * 4 + 2]);
      acc[o4 * 4 + 3] = fmaf(hv, w.w, acc[o4 * 4 + 3]);
    }
  }
  float* op = out + (size_t)t * D_OUT;
#pragma unroll
  for (int o = 0; o < D_OUT; o += 4) {
    float4 w = make_float4(acc[o], acc[o + 1], acc[o + 2], acc[o + 3]);
    *reinterpret_cast<float4*>(op + o) = w;
  }
}

// ------------- fused L1-dist + softmax(over i) + PV, flash style over NF -------------
// 2 j-columns per thread: the 12 ds_read_b128/row now feed 128 pairs (LDS-return-
// bandwidth was the r6 limit: 9.2 cy/ds measured). V regs shared by both slots.
__global__ __launch_bounds__(256, 3) void attn_kernel(
    const float* __restrict__ Wk, const float* __restrict__ Wq,
    const float* __restrict__ Vf, float* __restrict__ partial,
    int nchunks, int chlen) {
  // per buffer: K tile 64x32 = 512 float4, V tile 64x16 = 256 float4 -> 12 KB
  __shared__ float4 sTile[2][768];
  const int tid = threadIdx.x;
  const int j0 = blockIdx.x * 512 + tid;   // slot 0
  const int j1 = j0 + 256;                 // slot 1 (coalesced with slot 0)
  const int b = blockIdx.y;
  const int c = blockIdx.z;
  const int i0 = c * chlen;
  const int ntiles = chlen / TILE_I;

  float q[2][D_OUT];
  {
    const float* qp0 = Wq + ((size_t)b * NT + j0) * D_OUT;
    const float* qp1 = Wq + ((size_t)b * NT + j1) * D_OUT;
#pragma unroll
    for (int d = 0; d < D_OUT; d += 4) {
      float4 t4 = *reinterpret_cast<const float4*>(qp0 + d);
      q[0][d + 0] = t4.x; q[0][d + 1] = t4.y; q[0][d + 2] = t4.z; q[0][d + 3] = t4.w;
      float4 u4 = *reinterpret_cast<const float4*>(qp1 + d);
      q[1][d + 0] = u4.x; q[1][d + 1] = u4.y; q[1][d + 2] = u4.z; q[1][d + 3] = u4.w;
    }
  }

  constexpr float C2 = -0.72134752044448170368f;  // -log2(e)/2

  float m[2] = {-1e30f, -1e30f};  // running max, log2 domain
  float l[2] = {0.0f, 0.0f};
  float acc[2][D_V];
#pragma unroll
  for (int s = 0; s < 2; ++s)
#pragma unroll
    for (int k = 0; k < D_V; ++k) acc[s][k] = 0.0f;

  const float4* gK4 = reinterpret_cast<const float4*>(Wk + ((size_t)b * NF + i0) * D_OUT);
  const float4* gV4 = reinterpret_cast<const float4*>(Vf + ((size_t)b * NF + i0) * D_V);

  // prologue: stage tile 0 into buf 0
  {
    float4 f0 = gK4[tid];
    float4 f1 = gK4[256 + tid];
    float4 f2 = gV4[tid];
    sTile[0][tid] = f0;
    sTile[0][256 + tid] = f1;
    sTile[0][512 + tid] = f2;
  }
  __syncthreads();

  for (int t = 0; t < ntiles; ++t) {
    const int cur = t & 1;
    float4 f0, f1, f2;
    const bool more = (t + 1 < ntiles);
    if (more) {  // issue next tile's loads; they fly during the 64-row compute
      f0 = gK4[(size_t)(t + 1) * 512 + tid];
      f1 = gK4[(size_t)(t + 1) * 512 + 256 + tid];
      f2 = gV4[(size_t)(t + 1) * 256 + tid];
    }
    const float4* kb4 = &sTile[cur][0];
    const float4* vb4 = &sTile[cur][512];
    for (int r = 0; r < TILE_I; ++r) {
      const float4 k0 = kb4[0];
      const float4 k1 = kb4[1];
      const float4 k2 = kb4[2];
      const float4 k3 = kb4[3];
      const float4 k4 = kb4[4];
      const float4 k5 = kb4[5];
      const float4 k6 = kb4[6];
      const float4 k7 = kb4[7];
      kb4 += 8;

      // 4 chains x 2 slots, interleaved for ILP
      float a0 = fabsf(k0.x - q[0][0]);
      float b0 = fabsf(k0.x - q[1][0]);
      float a1 = fabsf(k0.y - q[0][1]);
      float b1 = fabsf(k0.y - q[1][1]);
      float a2 = fabsf(k0.z - q[0][2]);
      float b2 = fabsf(k0.z - q[1][2]);
      float a3 = fabsf(k0.w - q[0][3]);
      float b3 = fabsf(k0.w - q[1][3]);
      a0 += fabsf(k1.x - q[0][4]);  b0 += fabsf(k1.x - q[1][4]);
      a1 += fabsf(k1.y - q[0][5]);  b1 += fabsf(k1.y - q[1][5]);
      a2 += fabsf(k1.z - q[0][6]);  b2 += fabsf(k1.z - q[1][6]);
      a3 += fabsf(k1.w - q[0][7]);  b3 += fabsf(k1.w - q[1][7]);
      a0 += fabsf(k2.x - q[0][8]);  b0 += fabsf(k2.x - q[1][8]);
      a1 += fabsf(k2.y - q[0][9]);  b1 += fabsf(k2.y - q[1][9]);
      a2 += fabsf(k2.z - q[0][10]); b2 += fabsf(k2.z - q[1][10]);
      a3 += fabsf(k2.w - q[0][11]); b3 += fabsf(k2.w - q[1][11]);
      a0 += fabsf(k3.x - q[0][12]); b0 += fabsf(k3.x - q[1][12]);
      a1 += fabsf(k3.y - q[0][13]); b1 += fabsf(k3.y - q[1][13]);
      a2 += fabsf(k3.z - q[0][14]); b2 += fabsf(k3.z - q[1][14]);
      a3 += fabsf(k3.w - q[0][15]); b3 += fabsf(k3.w - q[1][15]);
      a0 += fabsf(k4.x - q[0][16]); b0 += fabsf(k4.x - q[1][16]);
      a1 += fabsf(k4.y - q[0][17]); b1 += fabsf(k4.y - q[1][17]);
      a2 += fabsf(k4.z - q[0][18]); b2 += fabsf(k4.z - q[1][18]);
      a3 += fabsf(k4.w - q[0][19]); b3 += fabsf(k4.w - q[1][19]);
      a0 += fabsf(k5.x - q[0][20]); b0 += fabsf(k5.x - q[1][20]);
      a1 += fabsf(k5.y - q[0][21]); b1 += fabsf(k5.y - q[1][21]);
      a2 += fabsf(k5.z - q[0][22]); b2 += fabsf(k5.z - q[1][22]);
      a3 += fabsf(k5.w - q[0][23]); b3 += fabsf(k5.w - q[1][23]);
      a0 += fabsf(k6.x - q[0][24]); b0 += fabsf(k6.x - q[1][24]);
      a1 += fabsf(k6.y - q[0][25]); b1 += fabsf(k6.y - q[1][25]);
      a2 += fabsf(k6.z - q[0][26]); b2 += fabsf(k6.z - q[1][26]);
      a3 += fabsf(k6.w - q[0][27]); b3 += fabsf(k6.w - q[1][27]);
      a0 += fabsf(k7.x - q[0][28]); b0 += fabsf(k7.x - q[1][28]);
      a1 += fabsf(k7.y - q[0][29]); b1 += fabsf(k7.y - q[1][29]);
      a2 += fabsf(k7.z - q[0][30]); b2 += fabsf(k7.z - q[1][30]);
      a3 += fabsf(k7.w - q[0][31]); b3 += fabsf(k7.w - q[1][31]);
      const float dist0 = (a0 + a1) + (a2 + a3);
      const float dist1 = (b0 + b1) + (b2 + b3);

      const float d20 = dist0 * dist0;
      const float d21 = dist1 * dist1;
      float parg0 = fmaf(C2, d20, -m[0]);
      float parg1 = fmaf(C2, d21, -m[1]);
      if (__any(fmaxf(parg0, parg1) > 4.0f)) {  // rare, wave-uniform rescale
        const float s20 = C2 * d20;
        const float mn0 = fmaxf(m[0], s20);
        const float al0 = fast_exp2(m[0] - mn0);
        l[0] *= al0;
#pragma unroll
        for (int k = 0; k < D_V; ++k) acc[0][k] *= al0;
        m[0] = mn0;
        parg0 = s20 - mn0;
        const float s21 = C2 * d21;
        const float mn1 = fmaxf(m[1], s21);
        const float al1 = fast_exp2(m[1] - mn1);
        l[1] *= al1;
#pragma unroll
        for (int k = 0; k < D_V; ++k) acc[1][k] *= al1;
        m[1] = mn1;
        parg1 = s21 - mn1;
      }
      const float p0 = fast_exp2(parg0);
      const float p1 = fast_exp2(parg1);

      // V read after dist chains (k regs dead) to cap liveness; shared by slots
      const float4 v0 = vb4[0];
      const float4 v1 = vb4[1];
      const float4 v2 = vb4[2];
      const float4 v3 = vb4[3];
      vb4 += 4;

      l[0] += p0;
      l[1] += p1;
      acc[0][0]  = fmaf(p0, v0.x, acc[0][0]);   acc[1][0]  = fmaf(p1, v0.x, acc[1][0]);
      acc[0][1]  = fmaf(p0, v0.y, acc[0][1]);   acc[1][1]  = fmaf(p1, v0.y, acc[1][1]);
      acc[0][2]  = fmaf(p0, v0.z, acc[0][2]);   acc[1][2]  = fmaf(p1, v0.z, acc[1][2]);
      acc[0][3]  = fmaf(p0, v0.w, acc[0][3]);   acc[1][3]  = fmaf(p1, v0.w, acc[1][3]);
      acc[0][4]  = fmaf(p0, v1.x, acc[0][4]);   acc[1][4]  = fmaf(p1, v1.x, acc[1][4]);
      acc[0][5]  = fmaf(p0, v1.y, acc[0][5]);   acc[1][5]  = fmaf(p1, v1.y, acc[1][5]);
      acc[0][6]  = fmaf(p0, v1.z, acc[0][6]);   acc[1][6]  = fmaf(p1, v1.z, acc[1][6]);
      acc[0][7]  = fmaf(p0, v1.w, acc[0][7]);   acc[1][7]  = fmaf(p1, v1.w, acc[1][7]);
      acc[0][8]  = fmaf(p0, v2.x, acc[0][8]);   acc[1][8]  = fmaf(p1, v2.x, acc[1][8]);
      acc[0][9]  = fmaf(p0, v2.y, acc[0][9]);   acc[1][9]  = fmaf(p1, v2.y, acc[1][9]);
      acc[0][10] = fmaf(p0, v2.z, acc[0][10]);  acc[1][10] = fmaf(p1, v2.z, acc[1][10]);
      acc[0][11] = fmaf(p0, v2.w, acc[0][11]);  acc[1][11] = fmaf(p1, v2.w, acc[1][11]);
      acc[0][12] = fmaf(p0, v3.x, acc[0][12]);  acc[1][12] = fmaf(p1, v3.x, acc[1][12]);
      acc[0][13] = fmaf(p0, v3.y, acc[0][13]);  acc[1][13] = fmaf(p1, v3.y, acc[1][13]);
      acc[0][14] = fmaf(p0, v3.z, acc[0][14]);  acc[1][14] = fmaf(p1, v3.z, acc[1][14]);
      acc[0][15] = fmaf(p0, v3.w, acc[0][15]);  acc[1][15] = fmaf(p1, v3.w, acc[1][15]);
    }
    if (more) {  // write-late: loads long since landed
      const int nxt = cur ^ 1;
      sTile[nxt][tid] = f0;
      sTile[nxt][256 + tid] = f1;
      sTile[nxt][512 + tid] = f2;
    }
    __syncthreads();
  }

  // SoA partials: partial[f * (nchunks*B*NT) + (c*B + b)*NT + j] -> coalesced
  const size_t fstride = (size_t)nchunks * B * NT;
  float* ps0 = partial + ((size_t)c * B + b) * NT + j0;
  float* ps1 = partial + ((size_t)c * B + b) * NT + j1;
  ps0[0] = m[0];
  ps1[0] = m[1];
  ps0[fstride] = l[0];
  ps1[fstride] = l[1];
#pragma unroll
  for (int k = 0; k < D_V; ++k) {
    ps0[(size_t)(2 + k) * fstride] = acc[0][k];
    ps1[(size_t)(2 + k) * fstride] = acc[1][k];
  }
}

// ---------------- combine NF-chunk partials -> output ----------------
__global__ __launch_bounds__(256) void combine_kernel(
    const float* __restrict__ partial, float* __restrict__ out, int nchunks) {
  const int t = blockIdx.x * 256 + threadIdx.x;  // = b*NT + j
  const size_t fstride = (size_t)nchunks * B * NT;
  float M = -1e30f;
  for (int c = 0; c < nchunks; ++c)
    M = fmaxf(M, partial[(size_t)c * (B * NT) + t]);
  float L = 0.0f;
  float acc[D_V];
#pragma unroll
  for (int k = 0; k < D_V; ++k) acc[k] = 0.0f;
  for (int c = 0; c < nchunks; ++c) {
    const size_t base = (size_t)c * (B * NT) + t;
    const float w = fast_exp2(partial[base] - M);
    L = fmaf(w, partial[fstride + base], L);
#pragma unroll
    for (int k = 0; k < D_V; ++k)
      acc[k] = fmaf(w, partial[(size_t)(2 + k) * fstride + base], acc[k]);
  }
  const float inv = 1.0f / L;
  float* op = out + (size_t)t * D_V;
#pragma unroll
  for (int k = 0; k < D_V; ++k) op[k] = acc[k] * inv;
}

extern "C" void kernel_launch(void* const* d_in, const int* in_sizes, int n_in,
                              void* d_out, int out_size, void* d_ws, size_t ws_size,
                              hipStream_t stream) {
  const float* coords_f = (const float*)d_in[0];
  const float* values_f = (const float*)d_in[1];
  const float* coords_t = (const float*)d_in[2];
  const float* Wk1 = (const float*)d_in[3];
  const float* bk1 = (const float*)d_in[4];
  const float* Wk2 = (const float*)d_in[5];
  const float* bk2 = (const float*)d_in[6];
  const float* Wq1 = (const float*)d_in[7];
  const float* bq1 = (const float*)d_in[8];
  const float* Wq2 = (const float*)d_in[9];
  const float* bq2 = (const float*)d_in[10];
  float* out = (float*)d_out;

  float* Wk = (float*)d_ws;                        // 4 MB
  float* Wq = Wk + (size_t)B * NF * D_OUT;         // 4 MB
  float* partial = Wq + (size_t)B * NT * D_OUT;

  const size_t fixed = (size_t)(B * NF * D_OUT + B * NT * D_OUT) * sizeof(float);
  int nchunks = 32;  // chlen = 128 = 2 tiles of 64
  while (nchunks > 1 &&
         fixed + (size_t)B * NT * nchunks * 18 * sizeof(float) > ws_size)
    nchunks >>= 1;
  const int chlen = NF / nchunks;

  hipLaunchKernelGGL(mlp_kernel, dim3(B * NF / 64), dim3(64), 0, stream,
                     coords_f, Wk1, bk1, Wk2, bk2, Wk);
  hipLaunchKernelGGL(mlp_kernel, dim3(B * NT / 64), dim3(64), 0, stream,
                     coords_t, Wq1, bq1, Wq2, bq2, Wq);
  hipLaunchKernelGGL(attn_kernel, dim3(NT / 512, B, nchunks), dim3(256), 0, stream,
                     Wk, Wq, values_f, partial, nchunks, chlen);
  hipLaunchKernelGGL(combine_kernel, dim3(B * NT / 256), dim3(256), 0, stream,
                     partial, out, nchunks);
}